// Round 1
// 279.024 us; speedup vs baseline: 1.0032x; 1.0032x over previous
//
#include <hip/hip_runtime.h>
#include <math.h>

// Problem constants: B=64, MAX_H=64, MAX_W=32, D=512, S=8, HID=64
#define NB    64
#define MAXH  64
#define MAXW  32
#define DCH   512
#define SS    8
#define HID   64

#define QTOTAL ((size_t)NB * MAXH * MAXW * DCH)   // 67,108,864 floats

typedef float f4  __attribute__((ext_vector_type(4)));
typedef short s8v __attribute__((ext_vector_type(8)));   // 8 bf16 (4 VGPRs)

__device__ __forceinline__ float gelu_exact(float x) {
    // jax.nn.gelu(approximate=False): x * 0.5 * (1 + erf(x/sqrt(2)))
    return 0.5f * x * (1.0f + erff(x * 0.70710678118654752440f));
}

__device__ __forceinline__ unsigned short bf16_rne(float x) {
    unsigned int u = __float_as_uint(x);
    unsigned int r = u + 0x7fffu + ((u >> 16) & 1u);
    return (unsigned short)(r >> 16);
}

// ---------------------------------------------------------------------------
// Prep: w2 (64x512 f32) -> bf16 table in MFMA fragment order (64 KB, d_ws).
// Lane l of a wave holds elems [k=(l>>4)*8+j][x=l&15], j=0..7 — this packing
// is IDENTICAL for the A-fragment (x=M-row) and B-fragment (x=N-col) of
// 16x16x32 bf16 MFMA. Table entry (kh, ct, lane):
//   k = 32*kh + (l>>4)*8 + j,  c = 16*ct + (l&15)
// Flat index = (kh*32 + ct)*64 + lane  (== tid below).
// ---------------------------------------------------------------------------
__global__ __launch_bounds__(256) void w2prep_kernel(
    const float* __restrict__ w2, s8v* __restrict__ w2b)
{
    const int tid  = blockIdx.x * 256 + threadIdx.x;   // 0..4095
    const int lane = tid & 63;
    const int ct   = (tid >> 6) & 31;
    const int kh   = tid >> 11;                        // 0..1
    const int q    = lane >> 4;
    const int m    = lane & 15;
    const int c    = ct * 16 + m;
    union { s8v v; unsigned short us[8]; } pk;
    #pragma unroll
    for (int j = 0; j < 8; ++j) {
        const int k = kh * 32 + q * 8 + j;
        pk.us[j] = bf16_rne(w2[k * DCH + c]);
    }
    w2b[tid] = pk.v;
}

// ---------------------------------------------------------------------------
// Main: one block = (b, i, half) -> 16 j x 512 c. 4 waves, each wave owns
// 128 channels = 8 MFMA tiles.
//
// TRANSPOSED MFMA (this round's change): compute D = w2^T · h^T = delta^T
// by swapping the operands:  A = w2-chunk fragment (16c x K), B = h fragment
// (K x 16j).  C/D layout: col = lane&15 = j_local, row = (lane>>4)*4 + r =
// c_local.  => each lane owns ONE j and FOUR CONSECUTIVE channels, so the
// bilinear seed is ds_read_b128 and the output store is global_store_dwordx4
// (was: 8x ds_read_b32 + 4x global_store_dword per tile).
// ---------------------------------------------------------------------------
__global__ __launch_bounds__(256) void hgqg_kernel(
    const float* __restrict__ canonical,  // (8,8,512)
    const float* __restrict__ w1,         // (2,64)
    const float* __restrict__ b1,         // (64,)
    const s8v*   __restrict__ w2b,        // bf16 fragment table (d_ws)
    const float* __restrict__ b2,         // (512,)
    const int*   __restrict__ hlist,      // (64,)
    const int*   __restrict__ wlist,      // (64,)
    float* __restrict__ out)              // queries flat, then mask flat
{
    // bijective swizzle: spreads (b,i) across CUs
    const int raw  = blockIdx.x;                 // 0..8191
    const int id   = (raw ^ (raw >> 7)) & 8191;
    const int i    = id & 63;
    const int half = (id >> 6) & 1;
    const int b    = id >> 7;
    const int blk  = (b << 6) | i;
    const int t    = threadIdx.x;

    int H = hlist[b]; H = min(max(H, 1), MAXH);
    int W = wlist[b]; W = min(max(W, 1), MAXW);

    const int jbase = half << 4;                 // 0 or 16

    f4* q4 = (f4*)(out + (size_t)blk * (MAXW * DCH)) + jbase * 128;

    if (half == 0 && t < MAXW) {
        out[QTOTAL + (size_t)blk * MAXW + t] = (i < H && t < W) ? 1.0f : 0.0f;
    }

    const f4 z = {0.f, 0.f, 0.f, 0.f};

    if (i >= H || jbase >= W) {
        #pragma unroll
        for (int r = 0; r < 8; ++r) q4[t + r * 256] = z;
        return;
    }

    // ---- per-row uniforms ----
    const float u    = (H > 1) ? (float)i / (float)(H - 1) : 0.0f;
    const float sy   = fminf(u * 7.0f, 7.0f);
    const int   y0   = (int)sy;
    const int   y1   = min(y0 + 1, SS - 1);
    const float wy   = sy - (float)y0;
    const float winv = (W > 1) ? 1.0f / (float)(W - 1) : 0.0f;

    // ---- stage A: y-lerped canonical rows -> LDS, padded stride 516 ----
    __shared__ __align__(16) float ri[SS * 516];     // 16.5 KB
    {
        const f4* can4 = (const f4*)canonical;
        #pragma unroll
        for (int rr = 0; rr < 4; ++rr) {
            const int idx = t + rr * 256;     // 0..1023
            const int x   = idx >> 7;
            const int c4  = idx & 127;
            const f4 a = can4[(y0 * SS + x) * 128 + c4];
            const f4 d = can4[(y1 * SS + x) * 128 + c4];
            *(f4*)&ri[x * 516 + c4 * 4] = a + wy * (d - a);
        }
    }

    // ---- stage B: hsh[jl][k] = gelu(u*w1[0][k] + v*w1[1][k] + b1[k]) ----
    __shared__ __align__(16) float hsh[16][68];      // padded: bank spread
    {
        const int jl = t >> 4;              // 0..15
        const int k0 = (t & 15) * 4;        // 0..60
        const float v = (float)(jbase + jl) * winv;
        #pragma unroll
        for (int kk = 0; kk < 4; ++kk) {
            const int k = k0 + kk;
            hsh[jl][k] = gelu_exact(u * w1[k] + v * w1[HID + k] + b1[k]);
        }
    }
    __syncthreads();

    // ---- wave decomposition ----
    const int l = t & 63;          // lane
    const int w = t >> 6;          // wave 0..3 -> channels [w*128, w*128+128)
    const int q = l >> 4;          // quad
    const int m = l & 15;          // lane-in-quad

    // h-fragments (used as MFMA *B* operand): lane holds h[j=m][k=q*8+j]
    union { s8v v; unsigned short us[8]; } A0, A1;
    {
        const float* hrow = &hsh[m][q * 8];
        #pragma unroll
        for (int j = 0; j < 8; ++j) {
            A0.us[j] = bf16_rne(hrow[j]);
            A1.us[j] = bf16_rne(hrow[32 + j]);
        }
    }

    // per-lane x-weights: this lane's single output row j = jbase + m
    const int   jl  = jbase + m;
    const float vv  = (float)jl * winv;
    const float sx  = fminf(vv * 7.0f, 7.0f);
    const int   x0  = (int)sx;
    const int   x1  = min(x0 + 1, SS - 1);
    const float wx  = sx - (float)x0;
    const bool  jok = (jl < W);

    float* orow = out + (size_t)blk * (MAXW * DCH) + (size_t)jl * DCH;

    #pragma unroll
    for (int tt = 0; tt < 8; ++tt) {
        const int ct = w * 8 + tt;           // c-tile 0..31
        const int cb = ct * 16 + q * 4;      // 4 consecutive channels / lane

        // seed C with bilinear + b2 (row r = channel cb+r, col m = j)
        const f4 f0 = *(const f4*)&ri[x0 * 516 + cb];
        const f4 f1 = *(const f4*)&ri[x1 * 516 + cb];
        const f4 bb = *(const f4*)&b2[cb];
        f4 acc = f0 + wx * (f1 - f0) + bb;

        // delta^T: two chained K=32 MFMAs, A = w2 fragment, B = h fragment
        const s8v b0  = w2b[ct * 64 + l];            // kh=0
        const s8v b1f = w2b[2048 + ct * 64 + l];     // kh=1
        acc = __builtin_amdgcn_mfma_f32_16x16x32_bf16(b0,  A0.v, acc, 0, 0, 0);
        acc = __builtin_amdgcn_mfma_f32_16x16x32_bf16(b1f, A1.v, acc, 0, 0, 0);

        // store 16 B contiguous per lane; mask is lane-uniform (j >= W -> 0)
        const f4 res = jok ? acc : z;
        *(f4*)(orow + cb) = res;
    }
}

extern "C" void kernel_launch(void* const* d_in, const int* in_sizes, int n_in,
                              void* d_out, int out_size, void* d_ws, size_t ws_size,
                              hipStream_t stream) {
    const float* canonical = (const float*)d_in[0];
    const float* w1        = (const float*)d_in[1];
    const float* b1        = (const float*)d_in[2];
    const float* w2        = (const float*)d_in[3];
    const float* b2        = (const float*)d_in[4];
    const int*   hlist     = (const int*)d_in[6];
    const int*   wlist     = (const int*)d_in[7];
    float* out = (float*)d_out;
    s8v*   w2b = (s8v*)d_ws;   // 64 KB bf16 fragment table

    w2prep_kernel<<<16, 256, 0, stream>>>(w2, w2b);
    hgqg_kernel<<<2 * NB * MAXH, 256, 0, stream>>>(
        canonical, w1, b1, w2b, b2, hlist, wlist, out);
}